// Round 5
// baseline (432.088 us; speedup 1.0000x reference)
//
#include <hip/hip_runtime.h>
#include <hip/hip_bf16.h>

// SimpleRNN(tanh) + Dense(5) + softmax, fused. B=8192, T=187, D=1, H=128, C=5.
//
// R5 == R3 design with the cvt_pkrtz type handling fixed cleanly (no UB).
//
// Design: 4 waves/block, each owns 32 hidden rows (j); 16-batch tile/block.
// Transposed recurrence h_pre^T = U^T h^T via mfma_f32_16x16x32_f16 (fp16
// single precision -- no hi/lo split): 8 MFMA/wave/step as two independent
// depth-4 chains. D-fragment of step s == B-fragment of step s+1 in-lane;
// wave w produces exactly B-frag T=w, kept in registers; the other 3 frags
// are exchanged through double-buffered LDS with ONE barrier per step.
// Grid 512 blocks x 256 thr -> 2 blocks/CU; co-resident blocks' barriers
// are independent, so their phases interleave on each SIMD (TLP=2).

#define BT 8192
#define TS 187
#define HD 128
#define NC 5

typedef float    f32x4  __attribute__((ext_vector_type(4)));
typedef _Float16 f16x8  __attribute__((ext_vector_type(8)));
typedef __fp16   fp16x2 __attribute__((ext_vector_type(2)));   // cvt_pkrtz return
typedef unsigned int u32;

__device__ __forceinline__ float tanh_fast(float v) {
    // tanh(v) = 1 - 2/(exp(2v)+1); exact at +-inf, no NaN (rcp(inf)=0).
    float e = __expf(2.0f * v);
    float r = __builtin_amdgcn_rcpf(e + 1.0f);
    return fmaf(-2.0f, r, 1.0f);
}

__device__ __forceinline__ u32 pk16(float a, float b) {
    fp16x2 p = __builtin_amdgcn_cvt_pkrtz(a, b);
    return __builtin_bit_cast(u32, p);
}

union f16x8_u { u32 w[4]; f16x8 v; };

__global__ __launch_bounds__(256, 2)
void rnn_fused(const float* __restrict__ xg, const float* __restrict__ wg,
               const float* __restrict__ ug, const float* __restrict__ bg,
               const float* __restrict__ wdg, const float* __restrict__ bdg,
               float* __restrict__ outg)
{
    __shared__ f16x8 xbuf[2][4][64];    // [dbuf][frag T][lane], 8 KB
    __shared__ float lg[4][16][NC];     // head partials

    const int tid  = threadIdx.x;
    const int w    = tid >> 6;          // wave 0..3 owns j in [32w, 32w+32)
    const int lane = tid & 63;
    const int l15  = lane & 15;         // batch col / j col for A-frag
    const int l4   = lane >> 4;         // 0..3
    const int b0   = blockIdx.x * 16;   // batch group

    // ---- U^T fragments, fp16. A-frag (M=j, K=i):
    //   m = l15 -> j = 32w + 16jt + l15 ; elem e -> i = 32T + 16(e>>2) + 4l4 + (e&3)
    f16x8 uf[2][4];
    #pragma unroll
    for (int jt = 0; jt < 2; ++jt) {
        const int j = 32*w + 16*jt + l15;
        #pragma unroll
        for (int T = 0; T < 4; ++T) {
            #pragma unroll
            for (int e = 0; e < 8; ++e) {
                const int i = 32*T + 16*(e>>2) + 4*l4 + (e&3);
                uf[jt][T][e] = (_Float16)ug[i*HD + j];
            }
        }
    }

    // ---- per-lane W, b  (D-frag rows j = 32w + 16jt + 4l4 + q)
    float wv0[4], wv1[4], bv0[4], bv1[4];
    #pragma unroll
    for (int q = 0; q < 4; ++q) {
        const int j = 32*w + 4*l4 + q;
        wv0[q] = wg[j];      bv0[q] = bg[j];
        wv1[q] = wg[j + 16]; bv1[q] = bg[j + 16];
    }

    // ---- state: h fragments (B-operand layout), h0 = 0
    f16x8 hfr[4];
    #pragma unroll
    for (int T = 0; T < 4; ++T)
        #pragma unroll
        for (int e = 0; e < 8; ++e) hfr[T][e] = (_Float16)0.0f;

    const float* xrow = xg + (long)(b0 + l15) * TS;
    float xv = xrow[0];

    f32x4 acc0, acc1;   // post-tanh h persists for the epilogue

    for (int s = 0; s < TS; ++s) {
        const int sn = (s + 1 < TS) ? s + 1 : TS - 1;
        float xnext = xrow[sn];                    // prefetch under the MFMAs

        // fp32 init: x*W + b
        #pragma unroll
        for (int q = 0; q < 4; ++q) {
            acc0[q] = fmaf(xv, wv0[q], bv0[q]);
            acc1[q] = fmaf(xv, wv1[q], bv1[q]);
        }

        // h_pre^T += U^T h^T  (two independent depth-4 chains)
        #pragma unroll
        for (int T = 0; T < 4; ++T) {
            acc0 = __builtin_amdgcn_mfma_f32_16x16x32_f16(uf[0][T], hfr[T], acc0, 0, 0, 0);
            acc1 = __builtin_amdgcn_mfma_f32_16x16x32_f16(uf[1][T], hfr[T], acc1, 0, 0, 0);
        }

        // tanh in place
        #pragma unroll
        for (int q = 0; q < 4; ++q) {
            acc0[q] = tanh_fast(acc0[q]);
            acc1[q] = tanh_fast(acc1[q]);
        }

        // pack own D-frag -> B-frag T=w: [acc0[0..3] | acc1[0..3]] as fp16
        f16x8_u Fu;
        Fu.w[0] = pk16(acc0[0], acc0[1]);
        Fu.w[1] = pk16(acc0[2], acc0[3]);
        Fu.w[2] = pk16(acc1[0], acc1[1]);
        Fu.w[3] = pk16(acc1[2], acc1[3]);
        const f16x8 F = Fu.v;

        // exchange: write own frag, barrier, read the other 3 (own from reg).
        // Double-buffered; reads of buf[s&1] complete before barrier s+1,
        // and the next write to buf[s&1] is after barrier s+1 -> race-free.
        xbuf[s & 1][w][lane] = F;
        __syncthreads();
        hfr[w] = F;
        #pragma unroll
        for (int t = 0; t < 4; ++t)
            if (t != w) hfr[t] = xbuf[s & 1][t][lane];

        xv = xnext;
    }

    // ---- head: logits = h @ Wd + bd ; softmax over 5 ----
    float p[NC];
    #pragma unroll
    for (int c = 0; c < NC; ++c) p[c] = 0.0f;
    #pragma unroll
    for (int q = 0; q < 4; ++q) {
        const int j0 = 32*w + 4*l4 + q;
        #pragma unroll
        for (int c = 0; c < NC; ++c) {
            p[c] = fmaf(acc0[q], wdg[j0*NC + c], p[c]);
            p[c] = fmaf(acc1[q], wdg[(j0+16)*NC + c], p[c]);
        }
    }
    #pragma unroll
    for (int c = 0; c < NC; ++c) {          // reduce over l4 groups
        p[c] += __shfl_xor(p[c], 16, 64);
        p[c] += __shfl_xor(p[c], 32, 64);
    }
    if (l4 == 0) {
        #pragma unroll
        for (int c = 0; c < NC; ++c) lg[w][l15][c] = p[c];
    }
    __syncthreads();

    if (tid < 16) {
        float l[NC];
        #pragma unroll
        for (int c = 0; c < NC; ++c)
            l[c] = bdg[c] + lg[0][tid][c] + lg[1][tid][c] + lg[2][tid][c] + lg[3][tid][c];
        float m = l[0];
        #pragma unroll
        for (int c = 1; c < NC; ++c) m = fmaxf(m, l[c]);
        float e[NC], ssum = 0.0f;
        #pragma unroll
        for (int c = 0; c < NC; ++c) { e[c] = __expf(l[c] - m); ssum += e[c]; }
        const float rs = 1.0f / ssum;
        #pragma unroll
        for (int c = 0; c < NC; ++c)
            outg[(long)(b0 + tid)*NC + c] = e[c] * rs;
    }
}

extern "C" void kernel_launch(void* const* d_in, const int* in_sizes, int n_in,
                              void* d_out, int out_size, void* d_ws, size_t ws_size,
                              hipStream_t stream) {
    const float* x  = (const float*)d_in[0];  // [8192][187][1]
    const float* W  = (const float*)d_in[1];  // [1][128]
    const float* U  = (const float*)d_in[2];  // [128][128]
    const float* b  = (const float*)d_in[3];  // [128]
    const float* Wd = (const float*)d_in[4];  // [128][5]
    const float* bd = (const float*)d_in[5];  // [5]
    float* out = (float*)d_out;               // [8192][5]

    rnn_fused<<<BT / 16, 256, 0, stream>>>(x, W, U, b, Wd, bd, out);
}

// Round 6
// 86.627 us; speedup vs baseline: 4.9879x; 4.9879x over previous
//
#include <hip/hip_runtime.h>
#include <hip/hip_bf16.h>

// SimpleRNN(tanh) + Dense(5) + softmax, fused. B=8192, T=187, D=1, H=128, C=5.
//
// R6: 8 waves/block (512 thr), wave w owns 16 hidden rows j in [16w,16w+16).
// Transposed recurrence h_pre^T = U^T h^T via mfma_f32_16x16x32_f16:
// 4 MFMA/wave/step. D-frag of step s == B-frag of step s+1 in-lane (rows
// 4*l4+q, cols l15 on both sides); wave w produces half-fragment
// (T=w>>1, half=w&1), exchanged via double-buffered LDS, ONE barrier/step.
// NO dynamic indexing of register arrays anywhere (R5's 4x regression was
// rule-#20 scratch demotion from hfr[w]). U fragments pinned via inline asm.
// Grid 512 blocks x 512 thr -> 2 blocks/CU -> 16 waves/CU = 4 waves/SIMD.

#define BT 8192
#define TS 187
#define HD 128
#define NC 5

typedef float    f32x4  __attribute__((ext_vector_type(4)));
typedef _Float16 f16x8  __attribute__((ext_vector_type(8)));
typedef __fp16   fp16x2 __attribute__((ext_vector_type(2)));   // cvt_pkrtz return
typedef unsigned int u32;
typedef u32      u32x2  __attribute__((ext_vector_type(2)));

__device__ __forceinline__ float tanh_fast(float v) {
    // tanh(v) = 1 - 2/(exp(2v)+1); exact at +-inf, no NaN (rcp(inf)=0).
    float e = __expf(2.0f * v);
    float r = __builtin_amdgcn_rcpf(e + 1.0f);
    return fmaf(-2.0f, r, 1.0f);
}

__device__ __forceinline__ u32 pk16(float a, float b) {
    fp16x2 p = __builtin_amdgcn_cvt_pkrtz(a, b);
    return __builtin_bit_cast(u32, p);
}

union frag_u { f16x8 v; u32 w[4]; };

// Pin a fragment's 4 dwords in VGPRs: makes them asm outputs so the
// allocator cannot rematerialize the feeding loads inside the loop.
__device__ __forceinline__ void pin_frag(f16x8& f) {
    frag_u pu; pu.v = f;
    asm volatile("" : "+v"(pu.w[0]), "+v"(pu.w[1]), "+v"(pu.w[2]), "+v"(pu.w[3]));
    f = pu.v;
}

__global__ __launch_bounds__(512, 4)
void rnn_fused(const float* __restrict__ xg, const float* __restrict__ wg,
               const float* __restrict__ ug, const float* __restrict__ bg,
               const float* __restrict__ wdg, const float* __restrict__ bdg,
               float* __restrict__ outg)
{
    __shared__ u32   xb[2][4][64][4];   // [dbuf][frag T][lane][dword], 8 KB
    __shared__ float lg[8][16][NC];     // head partials

    const int tid  = threadIdx.x;
    const int w    = tid >> 6;          // wave 0..7 owns j in [16w, 16w+16)
    const int lane = tid & 63;
    const int l15  = lane & 15;         // batch col / j col for A-frag
    const int l4   = lane >> 4;         // 0..3
    const int b0   = blockIdx.x * 16;   // batch group
    const int Tw   = w >> 1;            // fragment this wave feeds
    const int hw   = w & 1;             // which half (dwords 2hw, 2hw+1)

    // ---- U^T fragments, fp16. A-frag (M=j, K=i):
    //   m = l15 -> j = 16w + l15 ; elem e -> i = 32T + 16(e>>2) + 4l4 + (e&3)
    f16x8 uf0, uf1, uf2, uf3;
    {
        const int j = 16*w + l15;
        #pragma unroll
        for (int e = 0; e < 8; ++e) {
            const int i = 16*(e>>2) + 4*l4 + (e&3);
            uf0[e] = (_Float16)ug[(i      )*HD + j];
            uf1[e] = (_Float16)ug[(i + 32 )*HD + j];
            uf2[e] = (_Float16)ug[(i + 64 )*HD + j];
            uf3[e] = (_Float16)ug[(i + 96 )*HD + j];
        }
    }
    pin_frag(uf0); pin_frag(uf1); pin_frag(uf2); pin_frag(uf3);

    // ---- per-lane W, b  (D-frag rows j = 16w + 4l4 + q)
    float wv[4], bv[4];
    #pragma unroll
    for (int q = 0; q < 4; ++q) {
        const int j = 16*w + 4*l4 + q;
        wv[q] = wg[j];
        bv[q] = bg[j];
    }

    // ---- state: h fragments (B-operand layout), h0 = 0
    f16x8 h0 = (f16x8)(_Float16)0.0f;
    f16x8 h1 = h0, h2 = h0, h3 = h0;

    const float* xrow = xg + (long)(b0 + l15) * TS;
    float xv = xrow[0];

    f32x4 acc;   // post-tanh h persists for the epilogue

    for (int s = 0; s < TS; ++s) {
        const int sn = (s + 1 < TS) ? s + 1 : TS - 1;
        float xnext = xrow[sn];                    // prefetch under the MFMAs

        // fp32 init: x*W + b, then h_pre^T += U^T h^T (depth-4 chain; TLP=4
        // waves/SIMD keeps the MFMA pipe fed across waves)
        #pragma unroll
        for (int q = 0; q < 4; ++q) acc[q] = fmaf(xv, wv[q], bv[q]);
        acc = __builtin_amdgcn_mfma_f32_16x16x32_f16(uf0, h0, acc, 0, 0, 0);
        acc = __builtin_amdgcn_mfma_f32_16x16x32_f16(uf1, h1, acc, 0, 0, 0);
        acc = __builtin_amdgcn_mfma_f32_16x16x32_f16(uf2, h2, acc, 0, 0, 0);
        acc = __builtin_amdgcn_mfma_f32_16x16x32_f16(uf3, h3, acc, 0, 0, 0);

        // tanh
        #pragma unroll
        for (int q = 0; q < 4; ++q) acc[q] = tanh_fast(acc[q]);

        // pack 4 values -> 2 dwords; write own half-fragment to LDS
        u32x2 pk;
        pk[0] = pk16(acc[0], acc[1]);
        pk[1] = pk16(acc[2], acc[3]);
        *(u32x2*)&xb[s & 1][Tw][lane][2*hw] = pk;
        __syncthreads();

        // read the 4 full fragments (static indices only)
        h0 = *(const f16x8*)&xb[s & 1][0][lane][0];
        h1 = *(const f16x8*)&xb[s & 1][1][lane][0];
        h2 = *(const f16x8*)&xb[s & 1][2][lane][0];
        h3 = *(const f16x8*)&xb[s & 1][3][lane][0];

        xv = xnext;
    }

    // ---- head: logits = h @ Wd + bd ; softmax over 5 ----
    float p[NC];
    #pragma unroll
    for (int c = 0; c < NC; ++c) p[c] = 0.0f;
    #pragma unroll
    for (int q = 0; q < 4; ++q) {
        const int j = 16*w + 4*l4 + q;
        #pragma unroll
        for (int c = 0; c < NC; ++c)
            p[c] = fmaf(acc[q], wdg[j*NC + c], p[c]);
    }
    #pragma unroll
    for (int c = 0; c < NC; ++c) {          // reduce over l4 groups
        p[c] += __shfl_xor(p[c], 16, 64);
        p[c] += __shfl_xor(p[c], 32, 64);
    }
    if (l4 == 0) {
        #pragma unroll
        for (int c = 0; c < NC; ++c) lg[w][l15][c] = p[c];
    }
    __syncthreads();

    if (tid < 16) {
        float l[NC];
        #pragma unroll
        for (int c = 0; c < NC; ++c) {
            l[c] = bdg[c];
            #pragma unroll
            for (int ww = 0; ww < 8; ++ww) l[c] += lg[ww][tid][c];
        }
        float m = l[0];
        #pragma unroll
        for (int c = 1; c < NC; ++c) m = fmaxf(m, l[c]);
        float e[NC], ssum = 0.0f;
        #pragma unroll
        for (int c = 0; c < NC; ++c) { e[c] = __expf(l[c] - m); ssum += e[c]; }
        const float rs = 1.0f / ssum;
        #pragma unroll
        for (int c = 0; c < NC; ++c)
            outg[(long)(b0 + tid)*NC + c] = e[c] * rs;
    }
}

extern "C" void kernel_launch(void* const* d_in, const int* in_sizes, int n_in,
                              void* d_out, int out_size, void* d_ws, size_t ws_size,
                              hipStream_t stream) {
    const float* x  = (const float*)d_in[0];  // [8192][187][1]
    const float* W  = (const float*)d_in[1];  // [1][128]
    const float* U  = (const float*)d_in[2];  // [128][128]
    const float* b  = (const float*)d_in[3];  // [128]
    const float* Wd = (const float*)d_in[4];  // [128][5]
    const float* bd = (const float*)d_in[5];  // [5]
    float* out = (float*)d_out;               // [8192][5]

    rnn_fused<<<BT / 16, 512, 0, stream>>>(x, W, U, b, Wd, bd, out);
}

// Round 8
// 85.417 us; speedup vs baseline: 5.0586x; 1.0142x over previous
//
#include <hip/hip_runtime.h>
#include <hip/hip_bf16.h>

// SimpleRNN(tanh) + Dense(5) + softmax, fused. B=8192, T=187, D=1, H=128, C=5.
//
// R8 == R7 resubmitted after an infra failure (container died on connect;
// kernel audited clean: no UB, no OOB, LDS 22.5 KB, static reg indexing).
//
// R7 = R6 + three latency/issue trims (structure unchanged):
//  (1) x staged into LDS once (12 KB): NO global loads in the recurrence ->
//      __syncthreads' vmcnt(0) drain never waits on HBM/L3.
//  (2) MFMA chain split 2+2 (two independent chains, add folded into tanh).
//  (3) explicit 2-step unroll: compile-time LDS buffer index, no s&1 selects.
//
// Structure (R6, validated): 8 waves/block (512 thr), wave w owns 16 hidden
// rows j in [16w,16w+16); 16-batch tile/block. Transposed recurrence
// h_pre^T = U^T h^T via mfma_f32_16x16x32_f16 (4 MFMA/wave/step). D-frag of
// step s == B-frag of step s+1 in-lane; wave w produces half-fragment
// (T=w>>1, half=w&1) -> double-buffered LDS, ONE barrier/step. No dynamic
// register-array indexing (rule #20). Grid 512 x 512 thr -> 2 blocks/CU.

#define BT 8192
#define TS 187
#define HD 128
#define NC 5

typedef float    f32x4  __attribute__((ext_vector_type(4)));
typedef _Float16 f16x8  __attribute__((ext_vector_type(8)));
typedef __fp16   fp16x2 __attribute__((ext_vector_type(2)));   // cvt_pkrtz return
typedef unsigned int u32;
typedef u32      u32x2  __attribute__((ext_vector_type(2)));

__device__ __forceinline__ float tanh_fast(float v) {
    // tanh(v) = 1 - 2/(exp(2v)+1); exact at +-inf, no NaN (rcp(inf)=0).
    float e = __expf(2.0f * v);
    float r = __builtin_amdgcn_rcpf(e + 1.0f);
    return fmaf(-2.0f, r, 1.0f);
}

__device__ __forceinline__ u32 pk16(float a, float b) {
    fp16x2 p = __builtin_amdgcn_cvt_pkrtz(a, b);
    return __builtin_bit_cast(u32, p);
}

union frag_u { f16x8 v; u32 w[4]; };

// Pin a fragment's 4 dwords in VGPRs: the allocator cannot rematerialize
// the feeding loads inside the loop.
__device__ __forceinline__ void pin_frag(f16x8& f) {
    frag_u pu; pu.v = f;
    asm volatile("" : "+v"(pu.w[0]), "+v"(pu.w[1]), "+v"(pu.w[2]), "+v"(pu.w[3]));
    f = pu.v;
}

__global__ __launch_bounds__(512, 4)
void rnn_fused(const float* __restrict__ xg, const float* __restrict__ wg,
               const float* __restrict__ ug, const float* __restrict__ bg,
               const float* __restrict__ wdg, const float* __restrict__ bdg,
               float* __restrict__ outg)
{
    __shared__ u32   xb[2][4][64][4];   // [dbuf][frag T][lane][dword], 8 KB
    __shared__ float xs[TS][16];        // staged x, [time][batch col], ~12 KB
    __shared__ float lg[8][16][NC];     // head partials

    const int tid  = threadIdx.x;
    const int w    = tid >> 6;          // wave 0..7 owns j in [16w, 16w+16)
    const int lane = tid & 63;
    const int l15  = lane & 15;         // batch col / j col for A-frag
    const int l4   = lane >> 4;         // 0..3
    const int b0   = blockIdx.x * 16;   // batch group
    const int Tw   = w >> 1;            // fragment this wave feeds
    const int hw   = w & 1;             // which half (dwords 2hw, 2hw+1)

    // ---- stage x into LDS (one-time; coalesced: consecutive tid -> consecutive s)
    #pragma unroll
    for (int r = 0; r < 6; ++r) {
        const int idx = r * 512 + tid;          // 6*512 = 3072 >= 16*192
        const int bb  = idx / 192;              // 0..15
        const int ss  = idx % 192;
        if (ss < TS)
            xs[ss][bb] = xg[(long)(b0 + bb) * TS + ss];
    }

    // ---- U^T fragments, fp16. A-frag (M=j, K=i):
    //   m = l15 -> j = 16w + l15 ; elem e -> i = 32T + 16(e>>2) + 4l4 + (e&3)
    f16x8 uf0, uf1, uf2, uf3;
    {
        const int j = 16*w + l15;
        #pragma unroll
        for (int e = 0; e < 8; ++e) {
            const int i = 16*(e>>2) + 4*l4 + (e&3);
            uf0[e] = (_Float16)ug[(i      )*HD + j];
            uf1[e] = (_Float16)ug[(i + 32 )*HD + j];
            uf2[e] = (_Float16)ug[(i + 64 )*HD + j];
            uf3[e] = (_Float16)ug[(i + 96 )*HD + j];
        }
    }
    pin_frag(uf0); pin_frag(uf1); pin_frag(uf2); pin_frag(uf3);

    // ---- per-lane W, b  (D-frag rows j = 16w + 4l4 + q)
    float wv[4], bv[4];
    #pragma unroll
    for (int q = 0; q < 4; ++q) {
        const int j = 16*w + 4*l4 + q;
        wv[q] = wg[j];
        bv[q] = bg[j];
    }

    // ---- state: h fragments (B-operand layout), h0 = 0
    f16x8 h0 = (f16x8)(_Float16)0.0f;
    f16x8 h1 = h0, h2 = h0, h3 = h0;

    __syncthreads();                    // xs ready
    float xv = xs[0][l15];

    f32x4 acc;   // post-tanh h persists for the epilogue

    // One recurrence step; BUF is compile-time. Prefetches xs[SN].
#define STEP(BUF, SN)                                                       \
    {                                                                       \
        const float xnext = xs[(SN)][l15];                                  \
        f32x4 a0, a1;                                                       \
        _Pragma("unroll") for (int q = 0; q < 4; ++q) {                     \
            a0[q] = fmaf(xv, wv[q], bv[q]); a1[q] = 0.0f;                   \
        }                                                                   \
        a0 = __builtin_amdgcn_mfma_f32_16x16x32_f16(uf0, h0, a0, 0, 0, 0);  \
        a1 = __builtin_amdgcn_mfma_f32_16x16x32_f16(uf2, h2, a1, 0, 0, 0);  \
        a0 = __builtin_amdgcn_mfma_f32_16x16x32_f16(uf1, h1, a0, 0, 0, 0);  \
        a1 = __builtin_amdgcn_mfma_f32_16x16x32_f16(uf3, h3, a1, 0, 0, 0);  \
        _Pragma("unroll") for (int q = 0; q < 4; ++q)                       \
            acc[q] = tanh_fast(a0[q] + a1[q]);                              \
        u32x2 pk;                                                           \
        pk[0] = pk16(acc[0], acc[1]);                                       \
        pk[1] = pk16(acc[2], acc[3]);                                       \
        *(u32x2*)&xb[(BUF)][Tw][lane][2*hw] = pk;                           \
        __syncthreads();                                                    \
        h0 = *(const f16x8*)&xb[(BUF)][0][lane][0];                         \
        h1 = *(const f16x8*)&xb[(BUF)][1][lane][0];                         \
        h2 = *(const f16x8*)&xb[(BUF)][2][lane][0];                         \
        h3 = *(const f16x8*)&xb[(BUF)][3][lane][0];                         \
        xv = xnext;                                                         \
    }

    for (int k = 0; k < 93; ++k) {      // steps 0..185 as 93 unrolled pairs
        STEP(0, 2*k + 1);
        STEP(1, 2*k + 2);
    }
    STEP(0, TS - 1);                    // step 186 (buf 0; dummy prefetch)
#undef STEP

    // ---- head: logits = h @ Wd + bd ; softmax over 5 ----
    float p[NC];
    #pragma unroll
    for (int c = 0; c < NC; ++c) p[c] = 0.0f;
    #pragma unroll
    for (int q = 0; q < 4; ++q) {
        const int j = 16*w + 4*l4 + q;
        #pragma unroll
        for (int c = 0; c < NC; ++c)
            p[c] = fmaf(acc[q], wdg[j*NC + c], p[c]);
    }
    #pragma unroll
    for (int c = 0; c < NC; ++c) {          // reduce over l4 groups
        p[c] += __shfl_xor(p[c], 16, 64);
        p[c] += __shfl_xor(p[c], 32, 64);
    }
    if (l4 == 0) {
        #pragma unroll
        for (int c = 0; c < NC; ++c) lg[w][l15][c] = p[c];
    }
    __syncthreads();

    if (tid < 16) {
        float l[NC];
        #pragma unroll
        for (int c = 0; c < NC; ++c) {
            l[c] = bdg[c];
            #pragma unroll
            for (int ww = 0; ww < 8; ++ww) l[c] += lg[ww][tid][c];
        }
        float m = l[0];
        #pragma unroll
        for (int c = 1; c < NC; ++c) m = fmaxf(m, l[c]);
        float e[NC], ssum = 0.0f;
        #pragma unroll
        for (int c = 0; c < NC; ++c) { e[c] = __expf(l[c] - m); ssum += e[c]; }
        const float rs = 1.0f / ssum;
        #pragma unroll
        for (int c = 0; c < NC; ++c)
            outg[(long)(b0 + tid)*NC + c] = e[c] * rs;
    }
}

extern "C" void kernel_launch(void* const* d_in, const int* in_sizes, int n_in,
                              void* d_out, int out_size, void* d_ws, size_t ws_size,
                              hipStream_t stream) {
    const float* x  = (const float*)d_in[0];  // [8192][187][1]
    const float* W  = (const float*)d_in[1];  // [1][128]
    const float* U  = (const float*)d_in[2];  // [128][128]
    const float* b  = (const float*)d_in[3];  // [128]
    const float* Wd = (const float*)d_in[4];  // [128][5]
    const float* bd = (const float*)d_in[5];  // [5]
    float* out = (float*)d_out;               // [8192][5]

    rnn_fused<<<BT / 16, 512, 0, stream>>>(x, W, U, b, Wd, bd, out);
}